// Round 2
// baseline (453.426 us; speedup 1.0000x reference)
//
#include <hip/hip_runtime.h>
#include <hip/hip_cooperative_groups.h>
#include <math.h>

namespace cg = cooperative_groups;

#define EPSF 1e-5f

struct Params {
    const float *x;
    const float *fdWin, *fdbin, *fdWmid, *fdbmid, *fdWout, *fdbout, *fdg, *fdbt;
    const float *bdWin, *bdbin, *bdWmid, *bdbmid, *bdWout, *bdbout, *bdg, *bdbt;
    const float *scWin, *scbin, *scWmid, *scbmid, *scWout, *scbout, *scg, *scbt;
    const float *Wih, *Whh, *bih, *bhh, *mixW, *mixb;
    float *freq, *blk, *fseq, *Xg, *hseq, *mixed, *out;
};

__device__ __forceinline__ float sigmf(float x) { return 1.f / (1.f + __expf(-x)); }
__device__ __forceinline__ float tanhf_fast(float x) { return 1.f - 2.f / (__expf(2.f * x) + 1.f); }

__device__ __forceinline__ float pauliv(int p, int r, int c) {
    switch (p) {
        case 0: return (r == c) ? 1.f : 0.f;
        case 1: return (r != c) ? 1.f : 0.f;
        case 2: return (r == 0 && c == 1) ? 1.f : ((r == 1 && c == 0) ? -1.f : 0.f);
        default: return (r == c) ? ((r == 0) ? 1.f : -1.f) : 0.f;
    }
}

// 64-input MLP (fd or bd), 512 threads, one block.
__device__ void mlp64_body(const float* __restrict__ xin,
                           const float* __restrict__ Win,   // 64x128
                           const float* __restrict__ bin_,
                           const float* __restrict__ Wmid,  // 2x128x128
                           const float* __restrict__ bmid,
                           const float* __restrict__ Wout,  // 128x36
                           const float* __restrict__ bout,
                           const float* __restrict__ gamma,
                           const float* __restrict__ beta,
                           float* __restrict__ out,         // 32x36
                           float* sm)
{
    float* sX  = sm;          // 2048
    float* sA  = sm + 2048;   // 4096
    float* sB  = sm + 6144;   // 4096
    float* sMu = sm + 10240;  // 128
    float* sRs = sm + 10368;  // 128
    int tid = threadIdx.x;

    for (int idx = tid; idx < 2048; idx += 512) {
        int b = idx >> 6, c = idx & 63;
        sX[idx] = xin[b * 128 + c];
    }
    __syncthreads();

    for (int idx = tid; idx < 4096; idx += 512) {
        int b = idx >> 7, j = idx & 127;
        float acc = bin_[j];
        for (int c = 0; c < 64; ++c) acc = fmaf(sX[b * 64 + c], Win[c * 128 + j], acc);
        sA[idx] = fmaxf(acc, 0.f);
    }
    __syncthreads();

    float* cur = sA;
    float* nxt = sB;
    for (int l = 0; l < 3; ++l) {
        if (tid < 128) {
            float s = 0.f, s2 = 0.f;
            for (int b = 0; b < 32; ++b) {
                float v = cur[b * 128 + tid];
                s += v; s2 += v * v;
            }
            float mu = s * (1.f / 32.f);
            float var = s2 * (1.f / 32.f) - mu * mu;
            sMu[tid] = mu;
            sRs[tid] = rsqrtf(var + EPSF);
        }
        __syncthreads();
        for (int idx = tid; idx < 4096; idx += 512) {
            int j = idx & 127;
            cur[idx] = gamma[l * 128 + j] * (cur[idx] - sMu[j]) * sRs[j] + beta[l * 128 + j];
        }
        __syncthreads();
        if (l < 2) {
            for (int idx = tid; idx < 4096; idx += 512) {
                int b = idx >> 7, j = idx & 127;
                float acc = bmid[l * 128 + j];
                for (int c = 0; c < 128; ++c)
                    acc = fmaf(cur[b * 128 + c], Wmid[(l * 128 + c) * 128 + j], acc);
                nxt[idx] = fmaxf(acc, 0.f);
            }
            __syncthreads();
            float* t = cur; cur = nxt; nxt = t;
        } else {
            for (int idx = tid; idx < 32 * 36; idx += 512) {
                int b = idx / 36, j = idx - b * 36;
                float acc = bout[j];
                for (int c = 0; c < 128; ++c)
                    acc = fmaf(cur[b * 128 + c], Wout[c * 36 + j], acc);
                out[idx] = fmaxf(acc, 0.f);
            }
        }
    }
}

// per-s MLP (scalar input) -> cos -> fseq[t][b][s]; 512 threads, s = block id
__device__ void sc_body(int s, const Params& p, float* sm)
{
    float* sA  = sm;          // 4096
    float* sB  = sm + 4096;   // 4096
    float* sMu = sm + 8192;   // 128
    float* sRs = sm + 8320;   // 128
    int tid = threadIdx.x;
    const float* Wm = p.scWmid + (size_t)s * 2 * 128 * 128;
    const float* Wo = p.scWout + (size_t)s * 128 * 256;
    const float* gm = p.scg + s * 3 * 128;
    const float* bt = p.scbt + s * 3 * 128;

    for (int idx = tid; idx < 4096; idx += 512) {
        int b = idx >> 7, j = idx & 127;
        float acc = fmaf(p.freq[b * 36 + s], p.scWin[s * 128 + j], p.scbin[s * 128 + j]);
        sA[idx] = fmaxf(acc, 0.f);
    }
    __syncthreads();

    float* cur = sA;
    float* nxt = sB;
    for (int l = 0; l < 3; ++l) {
        if (tid < 128) {
            float sm_ = 0.f, s2 = 0.f;
            for (int b = 0; b < 32; ++b) {
                float v = cur[b * 128 + tid];
                sm_ += v; s2 += v * v;
            }
            float mu = sm_ * (1.f / 32.f);
            float var = s2 * (1.f / 32.f) - mu * mu;
            sMu[tid] = mu;
            sRs[tid] = rsqrtf(var + EPSF);
        }
        __syncthreads();
        for (int idx = tid; idx < 4096; idx += 512) {
            int j = idx & 127;
            cur[idx] = gm[l * 128 + j] * (cur[idx] - sMu[j]) * sRs[j] + bt[l * 128 + j];
        }
        __syncthreads();
        if (l < 2) {
            for (int idx = tid; idx < 4096; idx += 512) {
                int b = idx >> 7, j = idx & 127;
                float acc = p.scbmid[(s * 2 + l) * 128 + j];
                for (int c = 0; c < 128; ++c)
                    acc = fmaf(cur[b * 128 + c], Wm[(l * 128 + c) * 128 + j], acc);
                nxt[idx] = fmaxf(acc, 0.f);
            }
            __syncthreads();
            float* t = cur; cur = nxt; nxt = t;
        } else {
            for (int idx = tid; idx < 32 * 256; idx += 512) {
                int b = idx >> 8, n = idx & 255;
                float acc = p.scbout[s * 256 + n];
                for (int c = 0; c < 128; ++c)
                    acc = fmaf(cur[b * 128 + c], Wo[c * 256 + n], acc);
                float v = fmaxf(acc, 0.f);
                p.fseq[((size_t)n * 32 + b) * 36 + s] = __cosf(v);
            }
        }
    }
}

__global__ __launch_bounds__(512, 1) void fused_hamgen(Params p)
{
    cg::grid_group grid = cg::this_grid();
    __shared__ float sm[10496];   // 41984 B, unioned across phases
    const int bid = blockIdx.x;
    const int tid = threadIdx.x;

    // ---- Phase 1: fd MLP (block 0 only) --------------------------------
    if (bid == 0)
        mlp64_body(p.x, p.fdWin, p.fdbin, p.fdWmid, p.fdbmid, p.fdWout, p.fdbout,
                   p.fdg, p.fdbt, p.freq, sm);
    grid.sync();

    // ---- Phase 2: 36 per-s MLPs; bd MLP overlapped on block 36 ---------
    if (bid < 36) {
        sc_body(bid, p, sm);
    } else if (bid == 36) {
        mlp64_body(p.x + 64, p.bdWin, p.bdbin, p.bdWmid, p.bdbmid, p.bdWout, p.bdbout,
                   p.bdg, p.bdbt, p.blk, sm);
    }
    grid.sync();

    // ---- Phase 3: Xg[t][b][j] = bih+bhh + fseq[t][b][:] . Wih[j][:] ----
    {
        int t = bid;
        float* sF  = sm;          // 1152
        float* sWt = sm + 1152;   // 36 x 144 (transposed Wih)
        for (int idx = tid; idx < 1152; idx += 512) sF[idx] = p.fseq[(size_t)t * 1152 + idx];
        for (int idx = tid; idx < 5184; idx += 512) {
            int j = idx / 36, s2 = idx - j * 36;
            sWt[s2 * 144 + j] = p.Wih[idx];
        }
        __syncthreads();
        for (int idx = tid; idx < 4608; idx += 512) {
            int b = idx / 144, j = idx - b * 144;
            float acc = p.bih[j] + p.bhh[j];
            #pragma unroll
            for (int s2 = 0; s2 < 36; ++s2)
                acc = fmaf(sF[b * 36 + s2], sWt[s2 * 144 + j], acc);
            p.Xg[(size_t)t * 4608 + idx] = acc;
        }
    }
    grid.sync();

    // ---- Phase 4: LSTM recurrence (blocks 0..31, threads 0..191 work) --
    if (bid < 32) {
        int b = bid;
        float* sh = sm;        // 36
        float* sg = sm + 64;   // 144
        float w[36];
        if (tid < 144) {
            #pragma unroll
            for (int k = 0; k < 36; ++k) w[k] = p.Whh[tid * 36 + k];
        }
        if (tid < 36) sh[tid] = p.blk[b * 36 + tid];
        float c = 0.f;
        float xg = (tid < 144) ? p.Xg[(size_t)b * 144 + tid] : 0.f;
        const int type = tid / 36;
        __syncthreads();

        for (int t = 0; t < 256; ++t) {
            float act = 0.f;
            if (tid < 144) {
                float a0 = 0.f, a1 = 0.f, a2 = 0.f, a3 = 0.f;
                #pragma unroll
                for (int k = 0; k < 36; k += 4) {
                    a0 = fmaf(w[k + 0], sh[k + 0], a0);
                    a1 = fmaf(w[k + 1], sh[k + 1], a1);
                    a2 = fmaf(w[k + 2], sh[k + 2], a2);
                    a3 = fmaf(w[k + 3], sh[k + 3], a3);
                }
                float gate = xg + (a0 + a1) + (a2 + a3);
                float sarg = (type == 2) ? 2.f * gate : gate;
                float sv = sigmf(sarg);
                act = (type == 2) ? 2.f * sv - 1.f : sv;
            }
            if (t < 255 && tid < 144) xg = p.Xg[((size_t)(t + 1) * 32 + b) * 144 + tid];
            if (tid < 144) sg[tid] = act;
            __syncthreads();
            if (tid < 36) {
                float iv = sg[tid], fv = sg[36 + tid], gv = sg[72 + tid], ov = sg[108 + tid];
                c = fmaf(fv, c, iv * gv);
                float h = ov * tanhf_fast(c);
                sh[tid] = h;
                p.hseq[((size_t)b * 256 + t) * 36 + tid] = h;
            }
            __syncthreads();
        }
    }
    grid.sync();

    // ---- Phase 5: mixed[b][o][n] -----------------------------------------
    {
        int n = tid & 255;
        int half = tid >> 8;
        for (int job = bid * 2 + half; job < 1152; job += 512) {
            int b = job / 36, o = job - (job / 36) * 36;
            float acc = p.mixb[o];
            const float* wrow = p.mixW + o * 72;
            const float* bl = p.blk + b * 36;
            #pragma unroll
            for (int c2 = 0; c2 < 36; ++c2) acc = fmaf(wrow[c2], bl[c2], acc);
            const float* hp = p.hseq + ((size_t)b * 256 + n) * 36;
            #pragma unroll
            for (int u = 0; u < 36; ++u) acc = fmaf(wrow[36 + u], hp[u], acc);
            p.mixed[(size_t)job * 256 + n] = acc;
        }
    }
    grid.sync();

    // ---- Phase 6: assemble block-tridiagonal output (268 MB stores) ------
    {
        float* sChan = sm;       // 2 x 18
        float* sD    = sm + 40;  // 2 x 16
        int n = bid;
        int half = tid >> 8;
        int m = tid & 255;
        for (int iter = 0; iter < 32; ++iter) {
            int bg = iter * 2 + half;
            int g = bg & 1, b = bg >> 1;
            if (m < 18) {
                int ch = (m == 0) ? g : ((m == 1) ? 2 + g : 4 + 16 * g + (m - 2));
                sChan[half * 18 + m] = p.mixed[((size_t)(b * 36 + ch)) * 256 + n];
            }
            __syncthreads();
            if (m < 16) {
                int r = m >> 2, cc = m & 3;
                float acc = 0.f;
                #pragma unroll
                for (int k = 0; k < 16; ++k) {
                    float kv = pauliv(k >> 2, r >> 1, cc >> 1) * pauliv(k & 3, r & 1, cc & 1);
                    acc = fmaf(sChan[half * 18 + 2 + k], kv, acc);
                }
                sD[half * 16 + m] = acc;
            }
            __syncthreads();

            float4* outp = (float4*)p.out + ((size_t)bg * 1024 + 4 * n) * 256;
            const float* d = sD + half * 16;
            if (m == n) {
                #pragma unroll
                for (int r = 0; r < 4; ++r)
                    outp[r * 256 + m] = make_float4(d[r * 4 + 0], d[r * 4 + 1], d[r * 4 + 2], d[r * 4 + 3]);
            } else if (m == n - 1) {
                float v = sChan[half * 18 + 0];
                outp[0 * 256 + m] = make_float4(v, 0.f, 0.f, 0.f);
                outp[1 * 256 + m] = make_float4(0.f, v, 0.f, 0.f);
                outp[2 * 256 + m] = make_float4(0.f, 0.f, -v, 0.f);
                outp[3 * 256 + m] = make_float4(0.f, 0.f, 0.f, -v);
            } else if (m == n + 1) {
                float v = sChan[half * 18 + 1];
                outp[0 * 256 + m] = make_float4(v, 0.f, 0.f, 0.f);
                outp[1 * 256 + m] = make_float4(0.f, v, 0.f, 0.f);
                outp[2 * 256 + m] = make_float4(0.f, 0.f, -v, 0.f);
                outp[3 * 256 + m] = make_float4(0.f, 0.f, 0.f, -v);
            } else {
                float4 z = make_float4(0.f, 0.f, 0.f, 0.f);
                #pragma unroll
                for (int r = 0; r < 4; ++r) outp[r * 256 + m] = z;
            }
            __syncthreads();  // WAR: sChan/sD reused next iter
        }
    }
}

extern "C" void kernel_launch(void* const* d_in, const int* in_sizes, int n_in,
                              void* d_out, int out_size, void* d_ws, size_t ws_size,
                              hipStream_t stream) {
    Params p;
    p.x      = (const float*)d_in[0];
    p.fdWin  = (const float*)d_in[1];
    p.fdbin  = (const float*)d_in[2];
    p.fdWmid = (const float*)d_in[3];
    p.fdbmid = (const float*)d_in[4];
    p.fdWout = (const float*)d_in[5];
    p.fdbout = (const float*)d_in[6];
    p.fdg    = (const float*)d_in[7];
    p.fdbt   = (const float*)d_in[8];
    p.bdWin  = (const float*)d_in[9];
    p.bdbin  = (const float*)d_in[10];
    p.bdWmid = (const float*)d_in[11];
    p.bdbmid = (const float*)d_in[12];
    p.bdWout = (const float*)d_in[13];
    p.bdbout = (const float*)d_in[14];
    p.bdg    = (const float*)d_in[15];
    p.bdbt   = (const float*)d_in[16];
    p.scWin  = (const float*)d_in[17];
    p.scbin  = (const float*)d_in[18];
    p.scWmid = (const float*)d_in[19];
    p.scbmid = (const float*)d_in[20];
    p.scWout = (const float*)d_in[21];
    p.scbout = (const float*)d_in[22];
    p.scg    = (const float*)d_in[23];
    p.scbt   = (const float*)d_in[24];
    p.Wih    = (const float*)d_in[25];
    p.Whh    = (const float*)d_in[26];
    p.bih    = (const float*)d_in[27];
    p.bhh    = (const float*)d_in[28];
    p.mixW   = (const float*)d_in[29];
    p.mixb   = (const float*)d_in[30];

    float* ws = (float*)d_ws;
    p.freq  = ws;                 // 1152
    p.blk   = ws + 1152;          // 1152
    p.fseq  = ws + 2304;          // 294912
    p.Xg    = ws + 297216;        // 1179648
    p.hseq  = ws + 1476864;       // 294912
    p.mixed = ws + 1771776;       // 294912
    p.out   = (float*)d_out;

    void* args[] = { (void*)&p };
    hipLaunchCooperativeKernel((void*)fused_hamgen, dim3(256), dim3(512),
                               args, 0, stream);
}

// Round 4
// 424.943 us; speedup vs baseline: 1.0670x; 1.0670x over previous
//
#include <hip/hip_runtime.h>
#include <math.h>

#define EPSF 1e-5f
typedef __attribute__((ext_vector_type(2))) float f32x2;

__device__ __forceinline__ float pauliv(int p, int r, int c) {
    switch (p) {
        case 0: return (r == c) ? 1.f : 0.f;
        case 1: return (r != c) ? 1.f : 0.f;
        case 2: return (r == 0 && c == 1) ? 1.f : ((r == 1 && c == 0) ? -1.f : 0.f);
        default: return (r == c) ? ((r == 0) ? 1.f : -1.f) : 0.f;
    }
}

// ---------------------------------------------------------------------------
// Kernel 1: the two 64-input MLPs. block 0 = bd -> blk, block 1 = fd -> freq
// ---------------------------------------------------------------------------
__device__ void mlp64_body(const float* __restrict__ xin,
                           const float* __restrict__ Win,   // 64x128
                           const float* __restrict__ bin_,
                           const float* __restrict__ Wmid,  // 2x128x128
                           const float* __restrict__ bmid,
                           const float* __restrict__ Wout,  // 128x36
                           const float* __restrict__ bout,
                           const float* __restrict__ gamma,
                           const float* __restrict__ beta,
                           float* __restrict__ out)         // 32x36
{
    __shared__ float sX[2048];
    __shared__ float sA[4096];
    __shared__ float sB[4096];
    __shared__ float sMu[128], sRs[128];
    int tid = threadIdx.x;

    for (int idx = tid; idx < 2048; idx += 512) {
        int b = idx >> 6, c = idx & 63;
        sX[idx] = xin[b * 128 + c];
    }
    __syncthreads();

    for (int idx = tid; idx < 4096; idx += 512) {
        int b = idx >> 7, j = idx & 127;
        float acc = bin_[j];
        for (int c = 0; c < 64; ++c) acc = fmaf(sX[b * 64 + c], Win[c * 128 + j], acc);
        sA[idx] = fmaxf(acc, 0.f);
    }
    __syncthreads();

    float* cur = sA;
    float* nxt = sB;
    for (int l = 0; l < 3; ++l) {
        if (tid < 128) {
            float s = 0.f, s2 = 0.f;
            for (int b = 0; b < 32; ++b) {
                float v = cur[b * 128 + tid];
                s += v; s2 += v * v;
            }
            float mu = s * (1.f / 32.f);
            float var = s2 * (1.f / 32.f) - mu * mu;
            sMu[tid] = mu;
            sRs[tid] = rsqrtf(var + EPSF);
        }
        __syncthreads();
        for (int idx = tid; idx < 4096; idx += 512) {
            int j = idx & 127;
            cur[idx] = gamma[l * 128 + j] * (cur[idx] - sMu[j]) * sRs[j] + beta[l * 128 + j];
        }
        __syncthreads();
        if (l < 2) {
            for (int idx = tid; idx < 4096; idx += 512) {
                int b = idx >> 7, j = idx & 127;
                float acc = bmid[l * 128 + j];
                for (int c = 0; c < 128; ++c)
                    acc = fmaf(cur[b * 128 + c], Wmid[(l * 128 + c) * 128 + j], acc);
                nxt[idx] = fmaxf(acc, 0.f);
            }
            __syncthreads();
            float* t = cur; cur = nxt; nxt = t;
        } else {
            for (int idx = tid; idx < 1152; idx += 512) {
                int b = idx / 36, j = idx - b * 36;
                float acc = bout[j];
                for (int c = 0; c < 128; ++c)
                    acc = fmaf(cur[b * 128 + c], Wout[c * 36 + j], acc);
                out[idx] = fmaxf(acc, 0.f);
            }
        }
    }
}

__global__ __launch_bounds__(512) void k_mlp2(
    const float* __restrict__ x,
    const float* fdWin, const float* fdbin, const float* fdWmid, const float* fdbmid,
    const float* fdWout, const float* fdbout, const float* fdg, const float* fdbt,
    const float* bdWin, const float* bdbin, const float* bdWmid, const float* bdbmid,
    const float* bdWout, const float* bdbout, const float* bdg, const float* bdbt,
    float* freq, float* blk)
{
    if (blockIdx.x == 0)
        mlp64_body(x + 64, bdWin, bdbin, bdWmid, bdbmid, bdWout, bdbout, bdg, bdbt, blk);
    else
        mlp64_body(x, fdWin, fdbin, fdWmid, fdbmid, fdWout, fdbout, fdg, fdbt, freq);
}

// ---------------------------------------------------------------------------
// Kernel 2: 36 per-s MLPs -> cos -> fseq2[s][b][t]  (coalesced stores)
// ---------------------------------------------------------------------------
__global__ __launch_bounds__(512) void k_sc(
    const float* __restrict__ freq,  // [b][s]
    const float* __restrict__ Win,   // [s][128]
    const float* __restrict__ bin_,  // [s][128]
    const float* __restrict__ Wmid,  // [s][2][128][128]
    const float* __restrict__ bmid,  // [s][2][128]
    const float* __restrict__ Wout,  // [s][128][256]
    const float* __restrict__ bout,  // [s][256]
    const float* __restrict__ gamma, // [s][3][128]
    const float* __restrict__ beta,  // [s][3][128]
    float* __restrict__ fseq2)       // [s][b][t]
{
    int s = blockIdx.x, tid = threadIdx.x;
    __shared__ float sA[4096];
    __shared__ float sB[4096];
    __shared__ float sMu[128], sRs[128];
    const float* Wm = Wmid + (size_t)s * 2 * 128 * 128;
    const float* Wo = Wout + (size_t)s * 128 * 256;
    const float* gm = gamma + s * 3 * 128;
    const float* bt = beta + s * 3 * 128;

    for (int idx = tid; idx < 4096; idx += 512) {
        int b = idx >> 7, j = idx & 127;
        float acc = fmaf(freq[b * 36 + s], Win[s * 128 + j], bin_[s * 128 + j]);
        sA[idx] = fmaxf(acc, 0.f);
    }
    __syncthreads();

    float* cur = sA;
    float* nxt = sB;
    for (int l = 0; l < 3; ++l) {
        if (tid < 128) {
            float sm = 0.f, s2 = 0.f;
            for (int b = 0; b < 32; ++b) {
                float v = cur[b * 128 + tid];
                sm += v; s2 += v * v;
            }
            float mu = sm * (1.f / 32.f);
            float var = s2 * (1.f / 32.f) - mu * mu;
            sMu[tid] = mu;
            sRs[tid] = rsqrtf(var + EPSF);
        }
        __syncthreads();
        for (int idx = tid; idx < 4096; idx += 512) {
            int j = idx & 127;
            cur[idx] = gm[l * 128 + j] * (cur[idx] - sMu[j]) * sRs[j] + bt[l * 128 + j];
        }
        __syncthreads();
        if (l < 2) {
            // (32,128)@(128,128): thread = (bb, jj), 8 b's per thread, acc tile
            int jj = tid & 127, bb = tid >> 7;
            float acc[8];
            #pragma unroll
            for (int k = 0; k < 8; ++k) acc[k] = bmid[(s * 2 + l) * 128 + jj];
            for (int c = 0; c < 128; ++c) {
                float w = Wm[(l * 128 + c) * 128 + jj];
                #pragma unroll
                for (int k = 0; k < 8; ++k)
                    acc[k] = fmaf(cur[(bb + 4 * k) * 128 + c], w, acc[k]);
            }
            __syncthreads();
            #pragma unroll
            for (int k = 0; k < 8; ++k) nxt[(bb + 4 * k) * 128 + jj] = fmaxf(acc[k], 0.f);
            __syncthreads();
            float* t = cur; cur = nxt; nxt = t;
        } else {
            // (32,128)@(128,256) -> cos -> fseq2[s][b][n]
            int nn = tid & 255, bb2 = tid >> 8;
            float acc[16];
            #pragma unroll
            for (int k = 0; k < 16; ++k) acc[k] = bout[s * 256 + nn];
            for (int c = 0; c < 128; ++c) {
                float w = Wo[c * 256 + nn];
                #pragma unroll
                for (int k = 0; k < 16; ++k)
                    acc[k] = fmaf(cur[(bb2 + 2 * k) * 128 + c], w, acc[k]);
            }
            #pragma unroll
            for (int k = 0; k < 16; ++k) {
                float v = fmaxf(acc[k], 0.f);
                fseq2[((size_t)s * 32 + bb2 + 2 * k) * 256 + nn] = __cosf(v);
            }
        }
    }
}

// ---------------------------------------------------------------------------
// Kernel 3: Xg[b][t][j] = bih[j]+bhh[j] + sum_s fseq2[s][b][t] * Wih[j][s]
// ---------------------------------------------------------------------------
__global__ __launch_bounds__(512) void k_xg(
    const float* __restrict__ fseq2, const float* __restrict__ Wih,
    const float* __restrict__ bih, const float* __restrict__ bhh,
    float* __restrict__ Xg)
{
    int t = blockIdx.x, tid = threadIdx.x;
    __shared__ float sF[1152];       // [b][s]
    __shared__ float sWt[36 * 144];  // [s][j]
    for (int idx = tid; idx < 1152; idx += 512) {
        int s = idx >> 5, b = idx & 31;
        sF[b * 36 + s] = fseq2[(size_t)idx * 256 + t];
    }
    for (int idx = tid; idx < 5184; idx += 512) {
        int j = idx / 36, s = idx - j * 36;
        sWt[s * 144 + j] = Wih[idx];
    }
    __syncthreads();
    for (int idx = tid; idx < 4608; idx += 512) {
        int b = idx / 144, j = idx - b * 144;
        float acc = bih[j] + bhh[j];
        #pragma unroll
        for (int s = 0; s < 36; ++s)
            acc = fmaf(sF[b * 36 + s], sWt[s * 144 + j], acc);
        Xg[((size_t)b * 256 + t) * 144 + j] = acc;
    }
}

// ---------------------------------------------------------------------------
// Kernel 4: LSTM — one wave per sample, wave-synchronous, no LDS/barriers.
// Lane u (<36) owns all 4 gates of hidden unit u; h broadcast via __shfl.
// ---------------------------------------------------------------------------
__global__ __launch_bounds__(64) void k_lstm(
    const float* __restrict__ Xg,    // [b][t][144]
    const float* __restrict__ blk,   // [b][36]
    const float* __restrict__ Whh,   // [144][36]
    float* __restrict__ hseqT)       // [b][36][256]
{
    int b = blockIdx.x;
    int lane = threadIdx.x;
    int uu = lane < 36 ? lane : 35;
    bool active = lane < 36;

    f32x2 wif[36], wgo[36];
    #pragma unroll
    for (int k = 0; k < 36; ++k) {
        wif[k] = f32x2{Whh[uu * 36 + k], Whh[(36 + uu) * 36 + k]};
        wgo[k] = f32x2{Whh[(72 + uu) * 36 + k], Whh[(108 + uu) * 36 + k]};
    }
    float h = blk[b * 36 + uu];
    float c = 0.f;
    const float* xgb = Xg + (size_t)b * 256 * 144;
    f32x2 xif = f32x2{xgb[uu], xgb[36 + uu]};
    f32x2 xgo = f32x2{xgb[72 + uu], xgb[108 + uu]};
    float* hout = hseqT + ((size_t)b * 36 + uu) * 256;

    for (int t = 0; t < 256; ++t) {
        f32x2 nif = xif, ngo = xgo;
        if (t < 255) {
            const float* xp = xgb + (size_t)(t + 1) * 144;
            nif = f32x2{xp[uu], xp[36 + uu]};
            ngo = f32x2{xp[72 + uu], xp[108 + uu]};
        }
        f32x2 aif = xif, ago = xgo;
        #pragma unroll
        for (int k = 0; k < 36; ++k) {
            float hk = __shfl(h, k);
            f32x2 hk2 = f32x2{hk, hk};
            aif = __builtin_elementwise_fma(wif[k], hk2, aif);
            ago = __builtin_elementwise_fma(wgo[k], hk2, ago);
        }
        float iv = 1.f / (1.f + __expf(-aif.x));
        float fv = 1.f / (1.f + __expf(-aif.y));
        float gv = 1.f - 2.f / (__expf(2.f * ago.x) + 1.f);
        float ov = 1.f / (1.f + __expf(-ago.y));
        c = fmaf(fv, c, iv * gv);
        h = ov * (1.f - 2.f / (__expf(2.f * c) + 1.f));
        if (active) hout[t] = h;
        xif = nif; xgo = ngo;
    }
}

// ---------------------------------------------------------------------------
// Kernel 5: mixed[b][o][n]; block = (b, o-quarter); hseqT gives stride-1 lanes
// ---------------------------------------------------------------------------
__global__ __launch_bounds__(256) void k_mixed(
    const float* __restrict__ blk, const float* __restrict__ hseqT,
    const float* __restrict__ mixW, const float* __restrict__ mixb,
    float* __restrict__ mixed)
{
    int bq = blockIdx.x;
    int b = bq >> 2, oq = bq & 3;        // 9 o's per block
    int tid = threadIdx.x;
    __shared__ float sH[36 * 256];
    __shared__ float sW[9 * 36];
    __shared__ float sBase[9];
    for (int idx = tid; idx < 9216; idx += 256)
        sH[idx] = hseqT[(size_t)b * 9216 + idx];
    // BUG FIX (r3 -> r4): this fill needs 324 entries but the block has only
    // 256 threads; the old `if (tid < 324)` left sW[256..323] UNWRITTEN
    // (stale LDS -> garbage in o=7,8 channels -> absmax 3.7e8). Strided loop:
    for (int idx = tid; idx < 9 * 36; idx += 256) {
        int o = idx / 36, u = idx - o * 36;
        sW[idx] = mixW[(oq * 9 + o) * 72 + 36 + u];
    }
    if (tid < 9) {
        int o = oq * 9 + tid;
        float acc = mixb[o];
        for (int c = 0; c < 36; ++c) acc = fmaf(mixW[o * 72 + c], blk[b * 36 + c], acc);
        sBase[tid] = acc;
    }
    __syncthreads();
    int n = tid;
    #pragma unroll
    for (int o = 0; o < 9; ++o) {
        float acc = sBase[o];
        #pragma unroll
        for (int u = 0; u < 36; ++u)
            acc = fmaf(sW[o * 36 + u], sH[u * 256 + n], acc);
        mixed[((size_t)b * 36 + oq * 9 + o) * 256 + n] = acc;
    }
}

// ---------------------------------------------------------------------------
// Kernel 6: assemble output — barrier-free, LDS-free, uniform scalar loads
// ---------------------------------------------------------------------------
__global__ __launch_bounds__(256) void k_asm(
    const float* __restrict__ mixed, float* __restrict__ out)
{
    int wg = blockIdx.x;                  // (b*2+g)*256 + n
    int n = wg & 255, bg = wg >> 8;
    int g = bg & 1, b = bg >> 1;
    const float* mb = mixed + (size_t)b * 36 * 256 + n;
    float vSub = mb[(size_t)g * 256];
    float vSup = mb[(size_t)(2 + g) * 256];
    float ch[16];
    #pragma unroll
    for (int k = 0; k < 16; ++k) ch[k] = mb[(size_t)(4 + 16 * g + k) * 256];
    float d[16];
    #pragma unroll
    for (int e = 0; e < 16; ++e) {
        int r = e >> 2, cc = e & 3;
        float acc = 0.f;
        #pragma unroll
        for (int k = 0; k < 16; ++k) {
            float kv = pauliv(k >> 2, r >> 1, cc >> 1) * pauliv(k & 3, r & 1, cc & 1);
            if (kv == 1.f) acc = acc + ch[k];
            else if (kv == -1.f) acc = acc - ch[k];
        }
        d[e] = acc;
    }

    float4* outp = (float4*)out + ((size_t)bg * 1024 + 4 * n) * 256;
    int m = threadIdx.x;
    if (m == n) {
        #pragma unroll
        for (int r = 0; r < 4; ++r)
            outp[r * 256 + m] = make_float4(d[r * 4 + 0], d[r * 4 + 1], d[r * 4 + 2], d[r * 4 + 3]);
    } else if (m == n - 1) {
        outp[0 * 256 + m] = make_float4(vSub, 0.f, 0.f, 0.f);
        outp[1 * 256 + m] = make_float4(0.f, vSub, 0.f, 0.f);
        outp[2 * 256 + m] = make_float4(0.f, 0.f, -vSub, 0.f);
        outp[3 * 256 + m] = make_float4(0.f, 0.f, 0.f, -vSub);
    } else if (m == n + 1) {
        outp[0 * 256 + m] = make_float4(vSup, 0.f, 0.f, 0.f);
        outp[1 * 256 + m] = make_float4(0.f, vSup, 0.f, 0.f);
        outp[2 * 256 + m] = make_float4(0.f, 0.f, -vSup, 0.f);
        outp[3 * 256 + m] = make_float4(0.f, 0.f, 0.f, -vSup);
    } else {
        float4 z = make_float4(0.f, 0.f, 0.f, 0.f);
        #pragma unroll
        for (int r = 0; r < 4; ++r) outp[r * 256 + m] = z;
    }
}

// ---------------------------------------------------------------------------
extern "C" void kernel_launch(void* const* d_in, const int* in_sizes, int n_in,
                              void* d_out, int out_size, void* d_ws, size_t ws_size,
                              hipStream_t stream) {
    const float* x      = (const float*)d_in[0];
    const float* fdWin  = (const float*)d_in[1];
    const float* fdbin  = (const float*)d_in[2];
    const float* fdWmid = (const float*)d_in[3];
    const float* fdbmid = (const float*)d_in[4];
    const float* fdWout = (const float*)d_in[5];
    const float* fdbout = (const float*)d_in[6];
    const float* fdg    = (const float*)d_in[7];
    const float* fdbt   = (const float*)d_in[8];
    const float* bdWin  = (const float*)d_in[9];
    const float* bdbin  = (const float*)d_in[10];
    const float* bdWmid = (const float*)d_in[11];
    const float* bdbmid = (const float*)d_in[12];
    const float* bdWout = (const float*)d_in[13];
    const float* bdbout = (const float*)d_in[14];
    const float* bdg    = (const float*)d_in[15];
    const float* bdbt   = (const float*)d_in[16];
    const float* scWin  = (const float*)d_in[17];
    const float* scbin  = (const float*)d_in[18];
    const float* scWmid = (const float*)d_in[19];
    const float* scbmid = (const float*)d_in[20];
    const float* scWout = (const float*)d_in[21];
    const float* scbout = (const float*)d_in[22];
    const float* scg    = (const float*)d_in[23];
    const float* scbt   = (const float*)d_in[24];
    const float* Wih    = (const float*)d_in[25];
    const float* Whh    = (const float*)d_in[26];
    const float* bih    = (const float*)d_in[27];
    const float* bhh    = (const float*)d_in[28];
    const float* mixW   = (const float*)d_in[29];
    const float* mixb   = (const float*)d_in[30];

    float* ws    = (float*)d_ws;
    float* freq  = ws;                 // 1152            [b][s]
    float* blk   = ws + 1152;          // 1152            [b][s]
    float* fseq2 = ws + 2304;          // 294912          [s][b][t]
    float* Xg    = ws + 297216;        // 1179648         [b][t][144]
    float* hseqT = ws + 1476864;       // 294912          [b][u][t]
    float* mixed = ws + 1771776;       // 294912          [b][o][n]

    k_mlp2<<<2, 512, 0, stream>>>(x,
        fdWin, fdbin, fdWmid, fdbmid, fdWout, fdbout, fdg, fdbt,
        bdWin, bdbin, bdWmid, bdbmid, bdWout, bdbout, bdg, bdbt,
        freq, blk);
    k_sc<<<36, 512, 0, stream>>>(freq, scWin, scbin, scWmid, scbmid,
                                 scWout, scbout, scg, scbt, fseq2);
    k_xg<<<256, 512, 0, stream>>>(fseq2, Wih, bih, bhh, Xg);
    k_lstm<<<32, 64, 0, stream>>>(Xg, blk, Whh, hseqT);
    k_mixed<<<128, 256, 0, stream>>>(blk, hseqT, mixW, mixb, mixed);
    k_asm<<<16384, 256, 0, stream>>>(mixed, (float*)d_out);
}

// Round 6
// 333.949 us; speedup vs baseline: 1.3578x; 1.2725x over previous
//
#include <hip/hip_runtime.h>
#include <math.h>

#define EPSF 1e-5f
typedef __attribute__((ext_vector_type(2))) float f32x2;
typedef __attribute__((ext_vector_type(4))) float f32x4;

__device__ __forceinline__ float pauliv(int p, int r, int c) {
    switch (p) {
        case 0: return (r == c) ? 1.f : 0.f;
        case 1: return (r != c) ? 1.f : 0.f;
        case 2: return (r == 0 && c == 1) ? 1.f : ((r == 1 && c == 0) ? -1.f : 0.f);
        default: return (r == c) ? ((r == 0) ? 1.f : -1.f) : 0.f;
    }
}

// ---------------------------------------------------------------------------
// Kernel 1: the two 64-input MLPs. block 0 = bd -> blk, block 1 = fd -> freq
// ---------------------------------------------------------------------------
__device__ void mlp64_body(const float* __restrict__ xin,
                           const float* __restrict__ Win,   // 64x128
                           const float* __restrict__ bin_,
                           const float* __restrict__ Wmid,  // 2x128x128
                           const float* __restrict__ bmid,
                           const float* __restrict__ Wout,  // 128x36
                           const float* __restrict__ bout,
                           const float* __restrict__ gamma,
                           const float* __restrict__ beta,
                           float* __restrict__ out)         // 32x36
{
    __shared__ float sX[2048];
    __shared__ float sA[4096];
    __shared__ float sB[4096];
    __shared__ float sMu[128], sRs[128];
    int tid = threadIdx.x;

    for (int idx = tid; idx < 2048; idx += 512) {
        int b = idx >> 6, c = idx & 63;
        sX[idx] = xin[b * 128 + c];
    }
    __syncthreads();

    for (int idx = tid; idx < 4096; idx += 512) {
        int b = idx >> 7, j = idx & 127;
        float acc = bin_[j];
        for (int c = 0; c < 64; ++c) acc = fmaf(sX[b * 64 + c], Win[c * 128 + j], acc);
        sA[idx] = fmaxf(acc, 0.f);
    }
    __syncthreads();

    float* cur = sA;
    float* nxt = sB;
    for (int l = 0; l < 3; ++l) {
        if (tid < 128) {
            float s = 0.f, s2 = 0.f;
            for (int b = 0; b < 32; ++b) {
                float v = cur[b * 128 + tid];
                s += v; s2 += v * v;
            }
            float mu = s * (1.f / 32.f);
            float var = s2 * (1.f / 32.f) - mu * mu;
            sMu[tid] = mu;
            sRs[tid] = rsqrtf(var + EPSF);
        }
        __syncthreads();
        for (int idx = tid; idx < 4096; idx += 512) {
            int j = idx & 127;
            cur[idx] = gamma[l * 128 + j] * (cur[idx] - sMu[j]) * sRs[j] + beta[l * 128 + j];
        }
        __syncthreads();
        if (l < 2) {
            for (int idx = tid; idx < 4096; idx += 512) {
                int b = idx >> 7, j = idx & 127;
                float acc = bmid[l * 128 + j];
                for (int c = 0; c < 128; ++c)
                    acc = fmaf(cur[b * 128 + c], Wmid[(l * 128 + c) * 128 + j], acc);
                nxt[idx] = fmaxf(acc, 0.f);
            }
            __syncthreads();
            float* t = cur; cur = nxt; nxt = t;
        } else {
            for (int idx = tid; idx < 1152; idx += 512) {
                int b = idx / 36, j = idx - b * 36;
                float acc = bout[j];
                for (int c = 0; c < 128; ++c)
                    acc = fmaf(cur[b * 128 + c], Wout[c * 36 + j], acc);
                out[idx] = fmaxf(acc, 0.f);
            }
        }
    }
}

__global__ __launch_bounds__(512) void k_mlp2(
    const float* __restrict__ x,
    const float* fdWin, const float* fdbin, const float* fdWmid, const float* fdbmid,
    const float* fdWout, const float* fdbout, const float* fdg, const float* fdbt,
    const float* bdWin, const float* bdbin, const float* bdWmid, const float* bdbmid,
    const float* bdWout, const float* bdbout, const float* bdg, const float* bdbt,
    float* freq, float* blk)
{
    if (blockIdx.x == 0)
        mlp64_body(x + 64, bdWin, bdbin, bdWmid, bdbmid, bdWout, bdbout, bdg, bdbt, blk);
    else
        mlp64_body(x, fdWin, fdbin, fdWmid, fdbmid, fdWout, fdbout, fdg, fdbt, freq);
}

// ---------------------------------------------------------------------------
// Kernel 2: 36 per-s MLPs -> cos -> fseq2[s][b][t]  (coalesced stores)
// ---------------------------------------------------------------------------
__global__ __launch_bounds__(512) void k_sc(
    const float* __restrict__ freq,  // [b][s]
    const float* __restrict__ Win,   // [s][128]
    const float* __restrict__ bin_,  // [s][128]
    const float* __restrict__ Wmid,  // [s][2][128][128]
    const float* __restrict__ bmid,  // [s][2][128]
    const float* __restrict__ Wout,  // [s][128][256]
    const float* __restrict__ bout,  // [s][256]
    const float* __restrict__ gamma, // [s][3][128]
    const float* __restrict__ beta,  // [s][3][128]
    float* __restrict__ fseq2)       // [s][b][t]
{
    int s = blockIdx.x, tid = threadIdx.x;
    __shared__ float sA[4096];
    __shared__ float sB[4096];
    __shared__ float sMu[128], sRs[128];
    const float* Wm = Wmid + (size_t)s * 2 * 128 * 128;
    const float* Wo = Wout + (size_t)s * 128 * 256;
    const float* gm = gamma + s * 3 * 128;
    const float* bt = beta + s * 3 * 128;

    for (int idx = tid; idx < 4096; idx += 512) {
        int b = idx >> 7, j = idx & 127;
        float acc = fmaf(freq[b * 36 + s], Win[s * 128 + j], bin_[s * 128 + j]);
        sA[idx] = fmaxf(acc, 0.f);
    }
    __syncthreads();

    float* cur = sA;
    float* nxt = sB;
    for (int l = 0; l < 3; ++l) {
        if (tid < 128) {
            float sm = 0.f, s2 = 0.f;
            for (int b = 0; b < 32; ++b) {
                float v = cur[b * 128 + tid];
                sm += v; s2 += v * v;
            }
            float mu = sm * (1.f / 32.f);
            float var = s2 * (1.f / 32.f) - mu * mu;
            sMu[tid] = mu;
            sRs[tid] = rsqrtf(var + EPSF);
        }
        __syncthreads();
        for (int idx = tid; idx < 4096; idx += 512) {
            int j = idx & 127;
            cur[idx] = gm[l * 128 + j] * (cur[idx] - sMu[j]) * sRs[j] + bt[l * 128 + j];
        }
        __syncthreads();
        if (l < 2) {
            // (32,128)@(128,128): thread = (bb, jj), 8 b's per thread, acc tile
            int jj = tid & 127, bb = tid >> 7;
            float acc[8];
            #pragma unroll
            for (int k = 0; k < 8; ++k) acc[k] = bmid[(s * 2 + l) * 128 + jj];
            for (int c = 0; c < 128; ++c) {
                float w = Wm[(l * 128 + c) * 128 + jj];
                #pragma unroll
                for (int k = 0; k < 8; ++k)
                    acc[k] = fmaf(cur[(bb + 4 * k) * 128 + c], w, acc[k]);
            }
            __syncthreads();
            #pragma unroll
            for (int k = 0; k < 8; ++k) nxt[(bb + 4 * k) * 128 + jj] = fmaxf(acc[k], 0.f);
            __syncthreads();
            float* t = cur; cur = nxt; nxt = t;
        } else {
            // (32,128)@(128,256) -> cos -> fseq2[s][b][n]
            int nn = tid & 255, bb2 = tid >> 8;
            float acc[16];
            #pragma unroll
            for (int k = 0; k < 16; ++k) acc[k] = bout[s * 256 + nn];
            for (int c = 0; c < 128; ++c) {
                float w = Wo[c * 256 + nn];
                #pragma unroll
                for (int k = 0; k < 16; ++k)
                    acc[k] = fmaf(cur[(bb2 + 2 * k) * 128 + c], w, acc[k]);
            }
            #pragma unroll
            for (int k = 0; k < 16; ++k) {
                float v = fmaxf(acc[k], 0.f);
                fseq2[((size_t)s * 32 + bb2 + 2 * k) * 256 + nn] = __cosf(v);
            }
        }
    }
}

// ---------------------------------------------------------------------------
// Kernel 3: Xg[b][t][u][g] = bih+bhh + sum_s fseq2[s][b][t] * Wih[g*36+u][s]
// (gate-interleaved [u][4] layout so k_lstm reads one ds_read_b128 per lane)
// ---------------------------------------------------------------------------
__global__ __launch_bounds__(512) void k_xg(
    const float* __restrict__ fseq2, const float* __restrict__ Wih,
    const float* __restrict__ bih, const float* __restrict__ bhh,
    float* __restrict__ Xg)
{
    int t = blockIdx.x, tid = threadIdx.x;
    __shared__ float sF[1152];       // [b][s]
    __shared__ float sWt[36 * 144];  // [s][j]
    for (int idx = tid; idx < 1152; idx += 512) {
        int s = idx >> 5, b = idx & 31;
        sF[b * 36 + s] = fseq2[(size_t)idx * 256 + t];
    }
    for (int idx = tid; idx < 5184; idx += 512) {
        int j = idx / 36, s = idx - j * 36;
        sWt[s * 144 + j] = Wih[idx];
    }
    __syncthreads();
    for (int idx = tid; idx < 4608; idx += 512) {
        int b = idx / 144, j = idx - b * 144;
        int g = j / 36, u = j - g * 36;
        float acc = bih[j] + bhh[j];
        #pragma unroll
        for (int s = 0; s < 36; ++s)
            acc = fmaf(sF[b * 36 + s], sWt[s * 144 + j], acc);
        Xg[(((size_t)b * 256 + t) * 36 + u) * 4 + g] = acc;
    }
}

// ---------------------------------------------------------------------------
// Kernel 4: LSTM — one wave per sample, wave-synchronous.
//  * __launch_bounds__(64,1): Whh fragments (144 VGPRs) must stay in regs
//    (r4 had VGPR_Count=112 < 144 -> spills -> 189 us).
//  * readlane instead of __shfl: no ds_bpermute/lgkm latency per k.
//  * Xg staged in double-buffered LDS tiles (16 steps), reg-staged loads
//    issued a full tile ahead (HBM latency hides under compute).
// ---------------------------------------------------------------------------
#define TSTEPS 16
__global__ __launch_bounds__(64, 1) void k_lstm(
    const float* __restrict__ Xg,    // [b][t][36][4]  (i,f,g,o interleaved)
    const float* __restrict__ blk,   // [b][36]
    const float* __restrict__ Whh,   // [144][36]
    float* __restrict__ hseqT)       // [b][36][256]
{
    int b = blockIdx.x;
    int lane = threadIdx.x;
    int uu = lane < 36 ? lane : 35;
    bool active = lane < 36;

    __shared__ float lxg[2][TSTEPS * 144];   // 2 x 9216 B

    f32x2 wif[36], wgo[36];
    #pragma unroll
    for (int k = 0; k < 36; ++k) {
        wif[k] = f32x2{Whh[uu * 36 + k], Whh[(36 + uu) * 36 + k]};
        wgo[k] = f32x2{Whh[(72 + uu) * 36 + k], Whh[(108 + uu) * 36 + k]};
    }
    float h = blk[b * 36 + uu];
    float c = 0.f;
    const f32x4* xb = (const f32x4*)(Xg + (size_t)b * 256 * 144);  // [t][36] f32x4
    float* hout = hseqT + ((size_t)b * 36 + uu) * 256;

    // prologue: stage tile 0 into lxg[0]
    f32x4 stg[9];
    #pragma unroll
    for (int i = 0; i < 9; ++i) stg[i] = xb[i * 64 + lane];
    #pragma unroll
    for (int i = 0; i < 9; ++i) ((f32x4*)&lxg[0][0])[i * 64 + lane] = stg[i];

    for (int tt = 0; tt < 256 / TSTEPS; ++tt) {
        const int cur = tt & 1;
        // issue next tile's global loads now; they land during this tile's compute
        if (tt < 256 / TSTEPS - 1) {
            const f32x4* src = xb + (size_t)(tt + 1) * (TSTEPS * 36);
            #pragma unroll
            for (int i = 0; i < 9; ++i) stg[i] = src[i * 64 + lane];
        }

        #pragma unroll
        for (int s = 0; s < TSTEPS; ++s) {
            f32x4 xg4 = ((const f32x4*)&lxg[cur][s * 144])[uu];
            f32x2 a0 = f32x2{xg4.x, xg4.y};   // i,f
            f32x2 b0 = f32x2{xg4.z, xg4.w};   // g,o
            f32x2 a1 = f32x2{0.f, 0.f};
            f32x2 b1 = f32x2{0.f, 0.f};
            #pragma unroll
            for (int k = 0; k < 36; k += 2) {
                float h0 = __int_as_float(__builtin_amdgcn_readlane(__float_as_int(h), k));
                float h1 = __int_as_float(__builtin_amdgcn_readlane(__float_as_int(h), k + 1));
                a0 = __builtin_elementwise_fma(wif[k], f32x2{h0, h0}, a0);
                b0 = __builtin_elementwise_fma(wgo[k], f32x2{h0, h0}, b0);
                a1 = __builtin_elementwise_fma(wif[k + 1], f32x2{h1, h1}, a1);
                b1 = __builtin_elementwise_fma(wgo[k + 1], f32x2{h1, h1}, b1);
            }
            a0 += a1; b0 += b1;
            float iv = 1.f / (1.f + __expf(-a0.x));
            float fv = 1.f / (1.f + __expf(-a0.y));
            float gv = 1.f - 2.f / (__expf(2.f * b0.x) + 1.f);
            float ov = 1.f / (1.f + __expf(-b0.y));
            c = fmaf(fv, c, iv * gv);
            h = ov * (1.f - 2.f / (__expf(2.f * c) + 1.f));
            if (active) hout[tt * TSTEPS + s] = h;
        }

        // write next tile into the other buffer (single wave: no barrier,
        // compiler inserts vmcnt/lgkmcnt waits for the RAW on lxg)
        if (tt < 256 / TSTEPS - 1) {
            #pragma unroll
            for (int i = 0; i < 9; ++i)
                ((f32x4*)&lxg[cur ^ 1][0])[i * 64 + lane] = stg[i];
        }
    }
}

// ---------------------------------------------------------------------------
// Kernel 5: mixed[b][o][n]; block = (b, o-quarter); hseqT gives stride-1 lanes
// ---------------------------------------------------------------------------
__global__ __launch_bounds__(256) void k_mixed(
    const float* __restrict__ blk, const float* __restrict__ hseqT,
    const float* __restrict__ mixW, const float* __restrict__ mixb,
    float* __restrict__ mixed)
{
    int bq = blockIdx.x;
    int b = bq >> 2, oq = bq & 3;        // 9 o's per block
    int tid = threadIdx.x;
    __shared__ float sH[36 * 256];
    __shared__ float sW[9 * 36];
    __shared__ float sBase[9];
    for (int idx = tid; idx < 9216; idx += 256)
        sH[idx] = hseqT[(size_t)b * 9216 + idx];
    // needs 324 entries with 256 threads -> strided loop (r3 bug fix)
    for (int idx = tid; idx < 9 * 36; idx += 256) {
        int o = idx / 36, u = idx - o * 36;
        sW[idx] = mixW[(oq * 9 + o) * 72 + 36 + u];
    }
    if (tid < 9) {
        int o = oq * 9 + tid;
        float acc = mixb[o];
        for (int c = 0; c < 36; ++c) acc = fmaf(mixW[o * 72 + c], blk[b * 36 + c], acc);
        sBase[tid] = acc;
    }
    __syncthreads();
    int n = tid;
    #pragma unroll
    for (int o = 0; o < 9; ++o) {
        float acc = sBase[o];
        #pragma unroll
        for (int u = 0; u < 36; ++u)
            acc = fmaf(sW[o * 36 + u], sH[u * 256 + n], acc);
        mixed[((size_t)b * 36 + oq * 9 + o) * 256 + n] = acc;
    }
}

// ---------------------------------------------------------------------------
// Kernel 6: assemble output — barrier-free, LDS-free, nontemporal stores
// ---------------------------------------------------------------------------
__global__ __launch_bounds__(256) void k_asm(
    const float* __restrict__ mixed, float* __restrict__ out)
{
    int wg = blockIdx.x;                  // (b*2+g)*256 + n
    int n = wg & 255, bg = wg >> 8;
    int g = bg & 1, b = bg >> 1;
    const float* mb = mixed + (size_t)b * 36 * 256 + n;
    float vSub = mb[(size_t)g * 256];
    float vSup = mb[(size_t)(2 + g) * 256];
    float ch[16];
    #pragma unroll
    for (int k = 0; k < 16; ++k) ch[k] = mb[(size_t)(4 + 16 * g + k) * 256];
    float d[16];
    #pragma unroll
    for (int e = 0; e < 16; ++e) {
        int r = e >> 2, cc = e & 3;
        float acc = 0.f;
        #pragma unroll
        for (int k = 0; k < 16; ++k) {
            float kv = pauliv(k >> 2, r >> 1, cc >> 1) * pauliv(k & 3, r & 1, cc & 1);
            if (kv == 1.f) acc = acc + ch[k];
            else if (kv == -1.f) acc = acc - ch[k];
        }
        d[e] = acc;
    }

    f32x4* outp = (f32x4*)out + ((size_t)bg * 1024 + 4 * n) * 256;
    int m = threadIdx.x;
    if (m == n) {
        #pragma unroll
        for (int r = 0; r < 4; ++r)
            __builtin_nontemporal_store(
                f32x4{d[r * 4 + 0], d[r * 4 + 1], d[r * 4 + 2], d[r * 4 + 3]},
                &outp[r * 256 + m]);
    } else if (m == n - 1) {
        __builtin_nontemporal_store(f32x4{vSub, 0.f, 0.f, 0.f}, &outp[0 * 256 + m]);
        __builtin_nontemporal_store(f32x4{0.f, vSub, 0.f, 0.f}, &outp[1 * 256 + m]);
        __builtin_nontemporal_store(f32x4{0.f, 0.f, -vSub, 0.f}, &outp[2 * 256 + m]);
        __builtin_nontemporal_store(f32x4{0.f, 0.f, 0.f, -vSub}, &outp[3 * 256 + m]);
    } else if (m == n + 1) {
        __builtin_nontemporal_store(f32x4{vSup, 0.f, 0.f, 0.f}, &outp[0 * 256 + m]);
        __builtin_nontemporal_store(f32x4{0.f, vSup, 0.f, 0.f}, &outp[1 * 256 + m]);
        __builtin_nontemporal_store(f32x4{0.f, 0.f, -vSup, 0.f}, &outp[2 * 256 + m]);
        __builtin_nontemporal_store(f32x4{0.f, 0.f, 0.f, -vSup}, &outp[3 * 256 + m]);
    } else {
        f32x4 z = f32x4{0.f, 0.f, 0.f, 0.f};
        #pragma unroll
        for (int r = 0; r < 4; ++r)
            __builtin_nontemporal_store(z, &outp[r * 256 + m]);
    }
}

// ---------------------------------------------------------------------------
extern "C" void kernel_launch(void* const* d_in, const int* in_sizes, int n_in,
                              void* d_out, int out_size, void* d_ws, size_t ws_size,
                              hipStream_t stream) {
    const float* x      = (const float*)d_in[0];
    const float* fdWin  = (const float*)d_in[1];
    const float* fdbin  = (const float*)d_in[2];
    const float* fdWmid = (const float*)d_in[3];
    const float* fdbmid = (const float*)d_in[4];
    const float* fdWout = (const float*)d_in[5];
    const float* fdbout = (const float*)d_in[6];
    const float* fdg    = (const float*)d_in[7];
    const float* fdbt   = (const float*)d_in[8];
    const float* bdWin  = (const float*)d_in[9];
    const float* bdbin  = (const float*)d_in[10];
    const float* bdWmid = (const float*)d_in[11];
    const float* bdbmid = (const float*)d_in[12];
    const float* bdWout = (const float*)d_in[13];
    const float* bdbout = (const float*)d_in[14];
    const float* bdg    = (const float*)d_in[15];
    const float* bdbt   = (const float*)d_in[16];
    const float* scWin  = (const float*)d_in[17];
    const float* scbin  = (const float*)d_in[18];
    const float* scWmid = (const float*)d_in[19];
    const float* scbmid = (const float*)d_in[20];
    const float* scWout = (const float*)d_in[21];
    const float* scbout = (const float*)d_in[22];
    const float* scg    = (const float*)d_in[23];
    const float* scbt   = (const float*)d_in[24];
    const float* Wih    = (const float*)d_in[25];
    const float* Whh    = (const float*)d_in[26];
    const float* bih    = (const float*)d_in[27];
    const float* bhh    = (const float*)d_in[28];
    const float* mixW   = (const float*)d_in[29];
    const float* mixb   = (const float*)d_in[30];

    float* ws    = (float*)d_ws;
    float* freq  = ws;                 // 1152            [b][s]
    float* blk   = ws + 1152;          // 1152            [b][s]
    float* fseq2 = ws + 2304;          // 294912          [s][b][t]
    float* Xg    = ws + 297216;        // 1179648         [b][t][36][4]
    float* hseqT = ws + 1476864;       // 294912          [b][u][t]
    float* mixed = ws + 1771776;       // 294912          [b][o][n]

    k_mlp2<<<2, 512, 0, stream>>>(x,
        fdWin, fdbin, fdWmid, fdbmid, fdWout, fdbout, fdg, fdbt,
        bdWin, bdbin, bdWmid, bdbmid, bdWout, bdbout, bdg, bdbt,
        freq, blk);
    k_sc<<<36, 512, 0, stream>>>(freq, scWin, scbin, scWmid, scbmid,
                                 scWout, scbout, scg, scbt, fseq2);
    k_xg<<<256, 512, 0, stream>>>(fseq2, Wih, bih, bhh, Xg);
    k_lstm<<<32, 64, 0, stream>>>(Xg, blk, Whh, hseqT);
    k_mixed<<<128, 256, 0, stream>>>(blk, hseqT, mixW, mixb, mixed);
    k_asm<<<16384, 256, 0, stream>>>(mixed, (float*)d_out);
}

// Round 8
// 315.110 us; speedup vs baseline: 1.4389x; 1.0598x over previous
//
#include <hip/hip_runtime.h>
#include <math.h>

#define EPSF 1e-5f
typedef __attribute__((ext_vector_type(2))) float f32x2;
typedef __attribute__((ext_vector_type(4))) float f32x4;

__device__ __forceinline__ float pauliv(int p, int r, int c) {
    switch (p) {
        case 0: return (r == c) ? 1.f : 0.f;
        case 1: return (r != c) ? 1.f : 0.f;
        case 2: return (r == 0 && c == 1) ? 1.f : ((r == 1 && c == 0) ? -1.f : 0.f);
        default: return (r == c) ? ((r == 0) ? 1.f : -1.f) : 0.f;
    }
}

// ---------------------------------------------------------------------------
// Kernel 1: the two 64-input MLPs. block 0 = bd -> blk, block 1 = fd -> freq
// ---------------------------------------------------------------------------
__device__ void mlp64_body(const float* __restrict__ xin,
                           const float* __restrict__ Win,   // 64x128
                           const float* __restrict__ bin_,
                           const float* __restrict__ Wmid,  // 2x128x128
                           const float* __restrict__ bmid,
                           const float* __restrict__ Wout,  // 128x36
                           const float* __restrict__ bout,
                           const float* __restrict__ gamma,
                           const float* __restrict__ beta,
                           float* __restrict__ out)         // 32x36
{
    __shared__ float sX[2048];
    __shared__ float sA[4096];
    __shared__ float sB[4096];
    __shared__ float sMu[128], sRs[128];
    int tid = threadIdx.x;

    for (int idx = tid; idx < 2048; idx += 512) {
        int b = idx >> 6, c = idx & 63;
        sX[idx] = xin[b * 128 + c];
    }
    __syncthreads();

    for (int idx = tid; idx < 4096; idx += 512) {
        int b = idx >> 7, j = idx & 127;
        float acc = bin_[j];
        for (int c = 0; c < 64; ++c) acc = fmaf(sX[b * 64 + c], Win[c * 128 + j], acc);
        sA[idx] = fmaxf(acc, 0.f);
    }
    __syncthreads();

    float* cur = sA;
    float* nxt = sB;
    for (int l = 0; l < 3; ++l) {
        if (tid < 128) {
            float s = 0.f, s2 = 0.f;
            for (int b = 0; b < 32; ++b) {
                float v = cur[b * 128 + tid];
                s += v; s2 += v * v;
            }
            float mu = s * (1.f / 32.f);
            float var = s2 * (1.f / 32.f) - mu * mu;
            sMu[tid] = mu;
            sRs[tid] = rsqrtf(var + EPSF);
        }
        __syncthreads();
        for (int idx = tid; idx < 4096; idx += 512) {
            int j = idx & 127;
            cur[idx] = gamma[l * 128 + j] * (cur[idx] - sMu[j]) * sRs[j] + beta[l * 128 + j];
        }
        __syncthreads();
        if (l < 2) {
            for (int idx = tid; idx < 4096; idx += 512) {
                int b = idx >> 7, j = idx & 127;
                float acc = bmid[l * 128 + j];
                for (int c = 0; c < 128; ++c)
                    acc = fmaf(cur[b * 128 + c], Wmid[(l * 128 + c) * 128 + j], acc);
                nxt[idx] = fmaxf(acc, 0.f);
            }
            __syncthreads();
            float* t = cur; cur = nxt; nxt = t;
        } else {
            for (int idx = tid; idx < 1152; idx += 512) {
                int b = idx / 36, j = idx - b * 36;
                float acc = bout[j];
                for (int c = 0; c < 128; ++c)
                    acc = fmaf(cur[b * 128 + c], Wout[c * 36 + j], acc);
                out[idx] = fmaxf(acc, 0.f);
            }
        }
    }
}

__global__ __launch_bounds__(512) void k_mlp2(
    const float* __restrict__ x,
    const float* fdWin, const float* fdbin, const float* fdWmid, const float* fdbmid,
    const float* fdWout, const float* fdbout, const float* fdg, const float* fdbt,
    const float* bdWin, const float* bdbin, const float* bdWmid, const float* bdbmid,
    const float* bdWout, const float* bdbout, const float* bdg, const float* bdbt,
    float* freq, float* blk)
{
    if (blockIdx.x == 0)
        mlp64_body(x + 64, bdWin, bdbin, bdWmid, bdbmid, bdWout, bdbout, bdg, bdbt, blk);
    else
        mlp64_body(x, fdWin, fdbin, fdWmid, fdbmid, fdWout, fdbout, fdg, fdbt, freq);
}

// ---------------------------------------------------------------------------
// Kernel 2a: per-s MLP mids + all 3 BNs -> normalized activations actW[s]
// ---------------------------------------------------------------------------
__global__ __launch_bounds__(512) void k_sc1(
    const float* __restrict__ freq,  // [b][s]
    const float* __restrict__ Win,   // [s][128]
    const float* __restrict__ bin_,  // [s][128]
    const float* __restrict__ Wmid,  // [s][2][128][128]
    const float* __restrict__ bmid,  // [s][2][128]
    const float* __restrict__ gamma, // [s][3][128]
    const float* __restrict__ beta,  // [s][3][128]
    float* __restrict__ actW)        // [s][32][128]
{
    int s = blockIdx.x, tid = threadIdx.x;
    __shared__ float sA[4096];
    __shared__ float sB[4096];
    __shared__ float sMu[128], sRs[128];
    const float* Wm = Wmid + (size_t)s * 2 * 128 * 128;
    const float* gm = gamma + s * 3 * 128;
    const float* bt = beta + s * 3 * 128;

    for (int idx = tid; idx < 4096; idx += 512) {
        int b = idx >> 7, j = idx & 127;
        float acc = fmaf(freq[b * 36 + s], Win[s * 128 + j], bin_[s * 128 + j]);
        sA[idx] = fmaxf(acc, 0.f);
    }
    __syncthreads();

    float* cur = sA;
    float* nxt = sB;
    for (int l = 0; l < 3; ++l) {
        if (tid < 128) {
            float sm = 0.f, s2 = 0.f;
            for (int b = 0; b < 32; ++b) {
                float v = cur[b * 128 + tid];
                sm += v; s2 += v * v;
            }
            float mu = sm * (1.f / 32.f);
            float var = s2 * (1.f / 32.f) - mu * mu;
            sMu[tid] = mu;
            sRs[tid] = rsqrtf(var + EPSF);
        }
        __syncthreads();
        for (int idx = tid; idx < 4096; idx += 512) {
            int j = idx & 127;
            cur[idx] = gm[l * 128 + j] * (cur[idx] - sMu[j]) * sRs[j] + bt[l * 128 + j];
        }
        __syncthreads();
        if (l < 2) {
            int jj = tid & 127, bb = tid >> 7;
            float acc[8];
            #pragma unroll
            for (int k = 0; k < 8; ++k) acc[k] = bmid[(s * 2 + l) * 128 + jj];
            for (int c = 0; c < 128; ++c) {
                float w = Wm[(l * 128 + c) * 128 + jj];
                #pragma unroll
                for (int k = 0; k < 8; ++k)
                    acc[k] = fmaf(cur[(bb + 4 * k) * 128 + c], w, acc[k]);
            }
            __syncthreads();
            #pragma unroll
            for (int k = 0; k < 8; ++k) nxt[(bb + 4 * k) * 128 + jj] = fmaxf(acc[k], 0.f);
            __syncthreads();
            float* t = cur; cur = nxt; nxt = t;
        } else {
            for (int idx = tid; idx < 4096; idx += 512)
                actW[(size_t)s * 4096 + idx] = cur[idx];
        }
    }
}

// ---------------------------------------------------------------------------
// Kernel 2b: out-proj (128->256) + relu + cos -> fseq2[s][b][t]
// grid = 36*4 blocks: (s, n-quarter); 512 threads = 8 b-groups x 64 n
// ---------------------------------------------------------------------------
__global__ __launch_bounds__(512) void k_sc2(
    const float* __restrict__ actW,  // [s][32][128]
    const float* __restrict__ Wout,  // [s][128][256]
    const float* __restrict__ bout,  // [s][256]
    float* __restrict__ fseq2)       // [s][b][t]
{
    int bidx = blockIdx.x;
    int s = bidx >> 2, q = bidx & 3;
    int tid = threadIdx.x;
    __shared__ float sAct[4096];
    for (int idx = tid; idx < 4096; idx += 512)
        sAct[idx] = actW[(size_t)s * 4096 + idx];
    __syncthreads();

    int nn = (tid & 63) + q * 64;
    int bb = tid >> 6;                      // 0..7
    const float* Wo = Wout + (size_t)s * 128 * 256;
    float acc[4];
    #pragma unroll
    for (int k = 0; k < 4; ++k) acc[k] = bout[s * 256 + nn];
    #pragma unroll 4
    for (int c = 0; c < 128; ++c) {
        float w = Wo[c * 256 + nn];
        #pragma unroll
        for (int k = 0; k < 4; ++k)
            acc[k] = fmaf(sAct[(bb + 8 * k) * 128 + c], w, acc[k]);
    }
    #pragma unroll
    for (int k = 0; k < 4; ++k) {
        float v = fmaxf(acc[k], 0.f);
        fseq2[((size_t)s * 32 + bb + 8 * k) * 256 + nn] = __cosf(v);
    }
}

// ---------------------------------------------------------------------------
// Kernel 3: Xg[b][t][u][g] = bih+bhh + sum_s fseq2[s][b][t] * Wih[g*36+u][s]
// ---------------------------------------------------------------------------
__global__ __launch_bounds__(512) void k_xg(
    const float* __restrict__ fseq2, const float* __restrict__ Wih,
    const float* __restrict__ bih, const float* __restrict__ bhh,
    float* __restrict__ Xg)
{
    int t = blockIdx.x, tid = threadIdx.x;
    __shared__ float sF[1152];       // [b][s]
    __shared__ float sWt[36 * 144];  // [s][j]
    for (int idx = tid; idx < 1152; idx += 512) {
        int s = idx >> 5, b = idx & 31;
        sF[b * 36 + s] = fseq2[(size_t)idx * 256 + t];
    }
    for (int idx = tid; idx < 5184; idx += 512) {
        int j = idx / 36, s = idx - j * 36;
        sWt[s * 144 + j] = Wih[idx];
    }
    __syncthreads();
    for (int idx = tid; idx < 4608; idx += 512) {
        int b = idx / 144, j = idx - b * 144;
        int g = j / 36, u = j - g * 36;
        float acc = bih[j] + bhh[j];
        #pragma unroll
        for (int s = 0; s < 36; ++s)
            acc = fmaf(sF[b * 36 + s], sWt[s * 144 + j], acc);
        Xg[(((size_t)b * 256 + t) * 36 + u) * 4 + g] = acc;
    }
}

// ---------------------------------------------------------------------------
// Kernel 4: LSTM — unchanged from r6 (bit-identical) for clean attribution
// ---------------------------------------------------------------------------
#define TSTEPS 16
__global__ __launch_bounds__(64, 1) void k_lstm(
    const float* __restrict__ Xg,    // [b][t][36][4]  (i,f,g,o interleaved)
    const float* __restrict__ blk,   // [b][36]
    const float* __restrict__ Whh,   // [144][36]
    float* __restrict__ hseqT)       // [b][36][256]
{
    int b = blockIdx.x;
    int lane = threadIdx.x;
    int uu = lane < 36 ? lane : 35;
    bool active = lane < 36;

    __shared__ float lxg[2][TSTEPS * 144];   // 2 x 9216 B

    f32x2 wif[36], wgo[36];
    #pragma unroll
    for (int k = 0; k < 36; ++k) {
        wif[k] = f32x2{Whh[uu * 36 + k], Whh[(36 + uu) * 36 + k]};
        wgo[k] = f32x2{Whh[(72 + uu) * 36 + k], Whh[(108 + uu) * 36 + k]};
    }
    float h = blk[b * 36 + uu];
    float c = 0.f;
    const f32x4* xb = (const f32x4*)(Xg + (size_t)b * 256 * 144);  // [t][36] f32x4
    float* hout = hseqT + ((size_t)b * 36 + uu) * 256;

    f32x4 stg[9];
    #pragma unroll
    for (int i = 0; i < 9; ++i) stg[i] = xb[i * 64 + lane];
    #pragma unroll
    for (int i = 0; i < 9; ++i) ((f32x4*)&lxg[0][0])[i * 64 + lane] = stg[i];

    for (int tt = 0; tt < 256 / TSTEPS; ++tt) {
        const int cur = tt & 1;
        if (tt < 256 / TSTEPS - 1) {
            const f32x4* src = xb + (size_t)(tt + 1) * (TSTEPS * 36);
            #pragma unroll
            for (int i = 0; i < 9; ++i) stg[i] = src[i * 64 + lane];
        }

        #pragma unroll
        for (int s = 0; s < TSTEPS; ++s) {
            f32x4 xg4 = ((const f32x4*)&lxg[cur][s * 144])[uu];
            f32x2 a0 = f32x2{xg4.x, xg4.y};   // i,f
            f32x2 b0 = f32x2{xg4.z, xg4.w};   // g,o
            f32x2 a1 = f32x2{0.f, 0.f};
            f32x2 b1 = f32x2{0.f, 0.f};
            #pragma unroll
            for (int k = 0; k < 36; k += 2) {
                float h0 = __int_as_float(__builtin_amdgcn_readlane(__float_as_int(h), k));
                float h1 = __int_as_float(__builtin_amdgcn_readlane(__float_as_int(h), k + 1));
                a0 = __builtin_elementwise_fma(wif[k], f32x2{h0, h0}, a0);
                b0 = __builtin_elementwise_fma(wgo[k], f32x2{h0, h0}, b0);
                a1 = __builtin_elementwise_fma(wif[k + 1], f32x2{h1, h1}, a1);
                b1 = __builtin_elementwise_fma(wgo[k + 1], f32x2{h1, h1}, b1);
            }
            a0 += a1; b0 += b1;
            float iv = 1.f / (1.f + __expf(-a0.x));
            float fv = 1.f / (1.f + __expf(-a0.y));
            float gv = 1.f - 2.f / (__expf(2.f * b0.x) + 1.f);
            float ov = 1.f / (1.f + __expf(-b0.y));
            c = fmaf(fv, c, iv * gv);
            h = ov * (1.f - 2.f / (__expf(2.f * c) + 1.f));
            if (active) hout[tt * TSTEPS + s] = h;
        }

        if (tt < 256 / TSTEPS - 1) {
            #pragma unroll
            for (int i = 0; i < 9; ++i)
                ((f32x4*)&lxg[cur ^ 1][0])[i * 64 + lane] = stg[i];
        }
    }
}

// ---------------------------------------------------------------------------
// Kernel 5: mixed[b][o][n]; block = (b, o-quarter); hseqT gives stride-1 lanes
// ---------------------------------------------------------------------------
__global__ __launch_bounds__(256) void k_mixed(
    const float* __restrict__ blk, const float* __restrict__ hseqT,
    const float* __restrict__ mixW, const float* __restrict__ mixb,
    float* __restrict__ mixed)
{
    int bq = blockIdx.x;
    int b = bq >> 2, oq = bq & 3;        // 9 o's per block
    int tid = threadIdx.x;
    __shared__ float sH[36 * 256];
    __shared__ float sW[9 * 36];
    __shared__ float sBase[9];
    for (int idx = tid; idx < 9216; idx += 256)
        sH[idx] = hseqT[(size_t)b * 9216 + idx];
    for (int idx = tid; idx < 9 * 36; idx += 256) {
        int o = idx / 36, u = idx - o * 36;
        sW[idx] = mixW[(oq * 9 + o) * 72 + 36 + u];
    }
    if (tid < 9) {
        int o = oq * 9 + tid;
        float acc = mixb[o];
        for (int c = 0; c < 36; ++c) acc = fmaf(mixW[o * 72 + c], blk[b * 36 + c], acc);
        sBase[tid] = acc;
    }
    __syncthreads();
    int n = tid;
    #pragma unroll
    for (int o = 0; o < 9; ++o) {
        float acc = sBase[o];
        #pragma unroll
        for (int u = 0; u < 36; ++u)
            acc = fmaf(sW[o * 36 + u], sH[u * 256 + n], acc);
        mixed[((size_t)b * 36 + oq * 9 + o) * 256 + n] = acc;
    }
}

// ---------------------------------------------------------------------------
// Kernel 6a: zero the whole output (268 MB) — pure coalesced f32x4 stores
// ---------------------------------------------------------------------------
__global__ __launch_bounds__(256) void k_zero(float* __restrict__ out, long total4)
{
    f32x4* o = (f32x4*)out;
    f32x4 z = f32x4{0.f, 0.f, 0.f, 0.f};
    long stride = (long)gridDim.x * 256;
    for (long i = (long)blockIdx.x * 256 + threadIdx.x; i < total4; i += stride)
        o[i] = z;
}

// ---------------------------------------------------------------------------
// Kernel 6b: write only the nonzero tri-diagonal blocks (~3.2 MB)
// grid = 64 blocks (bg = b*2+g), 256 threads (n)   [r7 bug: was 512 blocks
// -> blocks 64..511 wrote 8x past the 268 MB output -> device fault]
// ---------------------------------------------------------------------------
__global__ __launch_bounds__(256) void k_sparse(
    const float* __restrict__ mixed, float* __restrict__ out)
{
    int bg = blockIdx.x;
    int g = bg & 1, b = bg >> 1;
    int n = threadIdx.x;
    const float* mb = mixed + (size_t)b * 36 * 256;
    float vSub = mb[(size_t)g * 256 + n];
    float vSup = mb[(size_t)(2 + g) * 256 + n];
    float ch[16];
    #pragma unroll
    for (int k = 0; k < 16; ++k) ch[k] = mb[(size_t)(4 + 16 * g + k) * 256 + n];
    float d[16];
    #pragma unroll
    for (int e = 0; e < 16; ++e) {
        int r = e >> 2, cc = e & 3;
        float acc = 0.f;
        #pragma unroll
        for (int k = 0; k < 16; ++k) {
            float kv = pauliv(k >> 2, r >> 1, cc >> 1) * pauliv(k & 3, r & 1, cc & 1);
            if (kv == 1.f) acc = acc + ch[k];
            else if (kv == -1.f) acc = acc - ch[k];
        }
        d[e] = acc;
    }

    float* base = out + (size_t)bg * 1024 * 1024;
    // diagonal 4x4 block: rows 4n..4n+3, cols 4n..4n+3
    #pragma unroll
    for (int r = 0; r < 4; ++r)
        *(f32x4*)(base + (size_t)(4 * n + r) * 1024 + 4 * n) =
            f32x4{d[r * 4 + 0], d[r * 4 + 1], d[r * 4 + 2], d[r * 4 + 3]};
    if (n > 0) {   // sub-diagonal: col block n-1, entry (r, r), signs +,+,-,-
        #pragma unroll
        for (int r = 0; r < 4; ++r)
            base[(size_t)(4 * n + r) * 1024 + 4 * (n - 1) + r] = (r < 2) ? vSub : -vSub;
    }
    if (n < 255) { // super-diagonal: col block n+1
        #pragma unroll
        for (int r = 0; r < 4; ++r)
            base[(size_t)(4 * n + r) * 1024 + 4 * (n + 1) + r] = (r < 2) ? vSup : -vSup;
    }
}

// ---------------------------------------------------------------------------
extern "C" void kernel_launch(void* const* d_in, const int* in_sizes, int n_in,
                              void* d_out, int out_size, void* d_ws, size_t ws_size,
                              hipStream_t stream) {
    const float* x      = (const float*)d_in[0];
    const float* fdWin  = (const float*)d_in[1];
    const float* fdbin  = (const float*)d_in[2];
    const float* fdWmid = (const float*)d_in[3];
    const float* fdbmid = (const float*)d_in[4];
    const float* fdWout = (const float*)d_in[5];
    const float* fdbout = (const float*)d_in[6];
    const float* fdg    = (const float*)d_in[7];
    const float* fdbt   = (const float*)d_in[8];
    const float* bdWin  = (const float*)d_in[9];
    const float* bdbin  = (const float*)d_in[10];
    const float* bdWmid = (const float*)d_in[11];
    const float* bdbmid = (const float*)d_in[12];
    const float* bdWout = (const float*)d_in[13];
    const float* bdbout = (const float*)d_in[14];
    const float* bdg    = (const float*)d_in[15];
    const float* bdbt   = (const float*)d_in[16];
    const float* scWin  = (const float*)d_in[17];
    const float* scbin  = (const float*)d_in[18];
    const float* scWmid = (const float*)d_in[19];
    const float* scbmid = (const float*)d_in[20];
    const float* scWout = (const float*)d_in[21];
    const float* scbout = (const float*)d_in[22];
    const float* scg    = (const float*)d_in[23];
    const float* scbt   = (const float*)d_in[24];
    const float* Wih    = (const float*)d_in[25];
    const float* Whh    = (const float*)d_in[26];
    const float* bih    = (const float*)d_in[27];
    const float* bhh    = (const float*)d_in[28];
    const float* mixW   = (const float*)d_in[29];
    const float* mixb   = (const float*)d_in[30];

    float* ws    = (float*)d_ws;
    float* freq  = ws;                 // 1152            [b][s]
    float* blk   = ws + 1152;          // 1152            [b][s]
    float* fseq2 = ws + 2304;          // 294912          [s][b][t]
    float* Xg    = ws + 297216;        // 1179648         [b][t][36][4]
    float* hseqT = ws + 1476864;       // 294912          [b][u][t]
    float* mixed = ws + 1771776;       // 294912          [b][o][n]
    // actW (147456 floats) aliases the Xg region: live only between k_sc1 and
    // k_sc2, both strictly before k_xg writes Xg. Keeps ws footprint == r6.
    float* actW  = Xg;

    float* out = (float*)d_out;
    long total4 = (long)out_size / 4;  // 268 MB / 16 B

    k_zero<<<2048, 256, 0, stream>>>(out, total4);
    k_mlp2<<<2, 512, 0, stream>>>(x,
        fdWin, fdbin, fdWmid, fdbmid, fdWout, fdbout, fdg, fdbt,
        bdWin, bdbin, bdWmid, bdbmid, bdWout, bdbout, bdg, bdbt,
        freq, blk);
    k_sc1<<<36, 512, 0, stream>>>(freq, scWin, scbin, scWmid, scbmid, scg, scbt, actW);
    k_sc2<<<144, 512, 0, stream>>>(actW, scWout, scbout, fseq2);
    k_xg<<<256, 512, 0, stream>>>(fseq2, Wih, bih, bhh, Xg);
    k_lstm<<<32, 64, 0, stream>>>(Xg, blk, Whh, hseqT);
    k_mixed<<<128, 256, 0, stream>>>(blk, hseqT, mixW, mixb, mixed);
    k_sparse<<<64, 256, 0, stream>>>(mixed, out);
}